// Round 8
// baseline (115.566 us; speedup 1.0000x reference)
//
#include <hip/hip_runtime.h>
#include <math.h>

#define D_DIM 2048
#define M_EV  16384
#define LCH   32
#define CCH   (M_EV / LCH)      // 512 chunks
#define SEG   32                // chunks per scan segment
#define NSEG  (CCH / SEG)       // 16 segments
#define BETA  1.0f

__device__ __forceinline__ float softplus_f(float x){
  float e = __expf(-fabsf(x));
  return fmaxf(x, 0.0f) + __logf(1.0f + e);
}

// float -> bf16 (RNE); inputs are finite non-negative here.
__device__ __forceinline__ unsigned short f2bf(float f){
  unsigned b = __float_as_uint(f);
  return (unsigned short)((b + 0x7FFFu + ((b >> 16) & 1u)) >> 16);
}
__device__ __forceinline__ float bf2f(unsigned short u){
  return __uint_as_float(((unsigned)u) << 16);
}

// T_max arrives as a 1-element array; decode int-vs-float defensively.
__device__ __forceinline__ float decode_T(const void* p){
  unsigned bits = *(const unsigned*)p;
  float fv = __uint_as_float(bits);
  return (fv >= 1e-3f && fv <= 1e7f) ? fv : (float)(int)bits;
}

__device__ __forceinline__ float wave_red(float v){
  #pragma unroll
  for (int o = 32; o > 0; o >>= 1) v += __shfl_down(v, o);
  return v;
}

// Fused small-work kernel (identical to R6). Block ranges:
//   [0,8)   : muw[j] = softplus(log_mu)+eps ; acc[2] += sum(mu)
//   [8,72)  : per event i: contrib[m_i] += 1-exp(-beta*(T-t_i))
//             AND Lsum scatter SL[c][m_i] += exp(-beta*(t_{(c+1)L}-t_i))
//   [72,74) : dchunk/cumdec per chunk (+ Aseg per segment in block 72)
__global__ void k_small(const float* __restrict__ t, const int* __restrict__ m,
                        const void* Tp, const float* __restrict__ log_mu,
                        float* __restrict__ muw, float* __restrict__ contrib,
                        float* __restrict__ SL, float* __restrict__ dchunk,
                        float* __restrict__ cumdec, float* __restrict__ Aseg,
                        float* __restrict__ acc){
  const int b = blockIdx.x, tid = threadIdx.x;
  if (b < 8){
    int j = b*256 + tid;
    float v = softplus_f(log_mu[j]) + 1e-6f;
    muw[j] = v;
    float s = wave_red(v);
    if ((tid & 63) == 0) atomicAdd(&acc[2], s);
  } else if (b < 72){
    int i = (b-8)*256 + tid;
    int d = m[i];
    float ti = t[i];
    float T = decode_T(Tp);
    atomicAdd(&contrib[d], 1.0f - __expf(-BETA * (T - ti)));
    int c = i >> 5;
    if (c < CCH - 1){                       // last chunk's carry is unused
      float tn = t[(c+1)*LCH];
      atomicAdd(&SL[(size_t)c * D_DIM + d], __expf(-BETA * (tn - ti)));
    }
  } else {
    int c = (b-72)*256 + tid;               // c in [0,512)
    float tc = t[c*LCH];
    dchunk[c] = (c < CCH-1) ? __expf(-BETA * (t[(c+1)*LCH] - tc)) : 1.0f;
    int s0c = (c >> 5) << 5;                // segment-start chunk
    cumdec[c] = __expf(-BETA * (tc - t[s0c*LCH]));
    if (b == 72 && tid < NSEG){
      int s = tid;
      Aseg[s] = (s < NSEG-1)
        ? __expf(-BETA * (t[(s+1)*SEG*LCH] - t[s*SEG*LCH])) : 1.0f;
    }
  }
}

// Fused: blocks [0,128) = per-segment local exclusive scan of SL (in-place,
// carry-out per segment) — verbatim R6 k_scan_local. Blocks [128,640) =
// sA = bf16(softplus(log_alpha)) + integral partial acc[1] — verbatim R6
// k_carry_alpha alpha range. The scan (tiny) hides under the alpha pass.
__global__ void k_scan_alpha(float* __restrict__ SL,
                             const float* __restrict__ dchunk,
                             float* __restrict__ Carry,
                             const float* __restrict__ la,
                             const float* __restrict__ contrib,
                             unsigned short* __restrict__ sA,
                             float* __restrict__ acc){
  const int b = blockIdx.x, tid = threadIdx.x;
  if (b < 128){
    const int seg = b >> 3, jb = b & 7;
    const int j = jb*256 + tid;
    const int c0 = seg * SEG;
    const size_t base = (size_t)c0 * D_DIM + j;
    float u = 0.f;
    float cur[4], nxt[4];
    #pragma unroll
    for (int q = 0; q < 4; ++q) cur[q] = SL[base + (size_t)q * D_DIM];
    for (int g = 0; g < SEG; g += 4){
      #pragma unroll
      for (int q = 0; q < 4; ++q)
        nxt[q] = (g+4 < SEG) ? SL[base + (size_t)(g+4+q) * D_DIM] : 0.f;
      #pragma unroll
      for (int q = 0; q < 4; ++q){
        int c = c0 + g + q;
        float l = cur[q];
        SL[(size_t)c * D_DIM + j] = u;
        u = fmaf(dchunk[c], u, l);
      }
      #pragma unroll
      for (int q = 0; q < 4; ++q) cur[q] = nxt[q];
    }
    Carry[(size_t)seg * D_DIM + j] = u;
    return;
  }
  const int nthreads = 512*256;               // alpha-range threads
  int atid = (b-128)*256 + tid;
  const float4* la4 = (const float4*)la;
  ushort4* sA4 = (ushort4*)sA;
  float p = 0.f;
  #pragma unroll
  for (int u = 0; u < 8; ++u){
    int i4 = atid + u * nthreads;
    float4 x = la4[i4];
    float4 sp;
    sp.x = softplus_f(x.x); sp.y = softplus_f(x.y);
    sp.z = softplus_f(x.z); sp.w = softplus_f(x.w);
    ushort4 h;
    h.x = f2bf(sp.x); h.y = f2bf(sp.y); h.z = f2bf(sp.z); h.w = f2bf(sp.w);
    sA4[i4] = h;
    int col = (i4 * 4) & (D_DIM - 1);
    p = fmaf(sp.x, contrib[col+0], p);
    p = fmaf(sp.y, contrib[col+1], p);
    p = fmaf(sp.z, contrib[col+2], p);
    p = fmaf(sp.w, contrib[col+3], p);
  }
  __shared__ float red[4];
  float w = wave_red(p);
  int lane = tid & 63, wid = tid >> 6;
  if (lane == 0) red[wid] = w;
  __syncthreads();
  if (tid == 0) atomicAdd(&acc[1], red[0]+red[1]+red[2]+red[3]);
}

// Segment-carry scan: E[s][j] = state entering segment s (8 blocks).
__global__ void k_carry(const float* __restrict__ Carry,
                        const float* __restrict__ Aseg,
                        float* __restrict__ E){
  const int j = blockIdx.x*256 + threadIdx.x;
  float cr[NSEG];
  #pragma unroll
  for (int s = 0; s < NSEG; ++s) cr[s] = Carry[(size_t)s * D_DIM + j];
  float e = 0.f;
  #pragma unroll
  for (int s = 0; s < NSEG; ++s){
    E[(size_t)s * D_DIM + j] = e;
    e = fmaf(Aseg[s], e, cr[s]);
  }
}

// One block (512 thr = 8 waves) per chunk. Decomposed (no sequential S):
//   lam_k = mu[d_k] + e^{-(t_k-t0)} * (sA[d_k] . S0)
//                   + sum_{i<k} e^{-(t_k-t_i)} * sA[d_k][m_i]
// Wave w owns events 4w..4w+3. Lane holds 32 S0 cols in registers.
__global__ __launch_bounds__(512) void k_events(
    const float* __restrict__ t, const int* __restrict__ m,
    const unsigned short* __restrict__ sA, const float* __restrict__ muw,
    const float* __restrict__ SL, const float* __restrict__ E,
    const float* __restrict__ cumdec, float* __restrict__ acc,
    const void* Tp, float* __restrict__ out){
  __shared__ float S0[D_DIM];
  __shared__ float tl[LCH];
  __shared__ int   ml[LCH];
  __shared__ float wred[8];
  const int tid = threadIdx.x;          // 0..511
  const int c = blockIdx.x;
  const int seg = c >> 5;
  const float cd = cumdec[c];

  {
    const float4 sv = *(const float4*)(SL + (size_t)c  * D_DIM + tid*4);
    const float4 ev = *(const float4*)(E  + (size_t)seg * D_DIM + tid*4);
    float4 s;
    s.x = fmaf(ev.x, cd, sv.x); s.y = fmaf(ev.y, cd, sv.y);
    s.z = fmaf(ev.z, cd, sv.z); s.w = fmaf(ev.w, cd, sv.w);
    *(float4*)&S0[tid*4] = s;
  }
  if (tid < LCH){
    ml[tid] = m[c*LCH + tid];
    tl[tid] = t[c*LCH + tid];
  }
  __syncthreads();

  const int l = tid & 63, w = tid >> 6;
  const int l4 = l * 4;

  // lane's 32 S0 columns -> registers (one-time)
  float4 s0[8];
  #pragma unroll
  for (int u = 0; u < 8; ++u) s0[u] = *(const float4*)&S0[u*256 + l4];

  const float t0 = tl[0];
  float lgw = 0.f;
  #pragma unroll
  for (int q = 0; q < 4; ++q){
    const int k = w*4 + q;
    const int d = ml[k];
    const unsigned short* row = sA + (size_t)d * D_DIM;
    float p = 0.f;
    #pragma unroll
    for (int u = 0; u < 8; ++u){
      ushort4 a = *(const ushort4*)(row + u*256 + l4);
      p = fmaf(bf2f(a.x), s0[u].x, p);
      p = fmaf(bf2f(a.y), s0[u].y, p);
      p = fmaf(bf2f(a.z), s0[u].z, p);
      p = fmaf(bf2f(a.w), s0[u].w, p);
    }
    const float tk = tl[k];
    float g = 0.f;
    if (l < k) g = bf2f(row[ml[l]]) * __expf(tl[l] - tk);  // exact pair term
    p = fmaf(p, __expf(t0 - tk), g);
    float v = wave_red(p);
    if (l == 0) lgw += __logf(muw[d] + v + 1e-8f);
  }
  if (l == 0) wred[w] = lgw;
  __syncthreads();
  if (tid == 0){
    float lg = ((wred[0]+wred[1])+(wred[2]+wred[3]))
             + ((wred[4]+wred[5])+(wred[6]+wred[7]));
    atomicAdd(&acc[0], lg);
    __threadfence();                        // publish before taking ticket
    unsigned old = atomicAdd((unsigned*)&acc[3], 1u);
    if (old == CCH - 1){                    // last block: finalize
      float a0 = atomicAdd(&acc[0], 0.0f);  // device-scope reads
      float a1 = atomicAdd(&acc[1], 0.0f);
      float a2 = atomicAdd(&acc[2], 0.0f);
      float T = decode_T(Tp);
      out[0] = a0 - (T * a2 + a1 * (1.0f / BETA));
    }
  }
}

extern "C" void kernel_launch(void* const* d_in, const int* in_sizes, int n_in,
                              void* d_out, int out_size, void* d_ws, size_t ws_size,
                              hipStream_t stream) {
  const float* t_events  = (const float*)d_in[0];
  const int*   marks     = (const int*)  d_in[1];
  const void*  Tp        =               d_in[2];
  const float* log_mu    = (const float*)d_in[3];
  const float* log_alpha = (const float*)d_in[4];
  float* out = (float*)d_out;

  // ws layout (floats), zeroed region first:
  // SL[CCH*D] | contrib[D] | acc[16] || Carry[NSEG*D] | E[NSEG*D] | muw[D]
  //   | dchunk[CCH] | cumdec[CCH] | Aseg[NSEG] | sA[D*D bf16]
  float* ws      = (float*)d_ws;
  float* SL      = ws;
  float* contrib = SL + (size_t)CCH * D_DIM;
  float* acc     = contrib + D_DIM;
  float* Carry   = acc + 16;
  float* E       = Carry + (size_t)NSEG * D_DIM;
  float* muw     = E + (size_t)NSEG * D_DIM;
  float* dchunk  = muw + D_DIM;
  float* cumdec  = dchunk + CCH;
  float* Aseg    = cumdec + CCH;
  unsigned short* sA = (unsigned short*)(Aseg + NSEG);  // 16B-aligned offset

  size_t zero_floats = (size_t)CCH * D_DIM + D_DIM + 16;
  hipMemsetAsync(d_ws, 0, zero_floats * sizeof(float), stream);

  k_small     <<<74, 256, 0, stream>>>(t_events, marks, Tp, log_mu, muw,
                                       contrib, SL, dchunk, cumdec, Aseg, acc);
  k_scan_alpha<<<640, 256, 0, stream>>>(SL, dchunk, Carry, log_alpha,
                                        contrib, sA, acc);
  k_carry     <<<8, 256, 0, stream>>>(Carry, Aseg, E);
  k_events    <<<CCH, 512, 0, stream>>>(t_events, marks, sA, muw,
                                        SL, E, cumdec, acc, Tp, out);
}

// Round 9
// 113.286 us; speedup vs baseline: 1.0201x; 1.0201x over previous
//
#include <hip/hip_runtime.h>
#include <math.h>

#define D_DIM 2048
#define M_EV  16384
#define LCH   32
#define CCH   (M_EV / LCH)      // 512 chunks
#define SEG   32                // chunks per scan segment
#define NSEG  (CCH / SEG)       // 16 segments
#define BETA  1.0f

__device__ __forceinline__ float softplus_f(float x){
  float e = __expf(-fabsf(x));
  return fmaxf(x, 0.0f) + __logf(1.0f + e);
}

// float -> bf16 (RNE); inputs are finite non-negative here.
__device__ __forceinline__ unsigned short f2bf(float f){
  unsigned b = __float_as_uint(f);
  return (unsigned short)((b + 0x7FFFu + ((b >> 16) & 1u)) >> 16);
}
__device__ __forceinline__ float bf2f(unsigned short u){
  return __uint_as_float(((unsigned)u) << 16);
}

// T_max arrives as a 1-element array; decode int-vs-float defensively.
__device__ __forceinline__ float decode_T(const void* p){
  unsigned bits = *(const unsigned*)p;
  float fv = __uint_as_float(bits);
  return (fv >= 1e-3f && fv <= 1e7f) ? fv : (float)(int)bits;
}

__device__ __forceinline__ float wave_red(float v){
  #pragma unroll
  for (int o = 32; o > 0; o >>= 1) v += __shfl_down(v, o);
  return v;
}

// Fused small-work kernel (identical to R6/R8). Block ranges:
//   [0,8)   : muw[j] = softplus(log_mu)+eps ; acc[2] += sum(mu)
//   [8,72)  : per event i: contrib[m_i] += 1-exp(-beta*(T-t_i))
//             AND Lsum scatter SL[c][m_i] += exp(-beta*(t_{(c+1)L}-t_i))
//   [72,74) : dchunk/cumdec per chunk (+ Aseg per segment in block 72)
__global__ void k_small(const float* __restrict__ t, const int* __restrict__ m,
                        const void* Tp, const float* __restrict__ log_mu,
                        float* __restrict__ muw, float* __restrict__ contrib,
                        float* __restrict__ SL, float* __restrict__ dchunk,
                        float* __restrict__ cumdec, float* __restrict__ Aseg,
                        float* __restrict__ acc){
  const int b = blockIdx.x, tid = threadIdx.x;
  if (b < 8){
    int j = b*256 + tid;
    float v = softplus_f(log_mu[j]) + 1e-6f;
    muw[j] = v;
    float s = wave_red(v);
    if ((tid & 63) == 0) atomicAdd(&acc[2], s);
  } else if (b < 72){
    int i = (b-8)*256 + tid;
    int d = m[i];
    float ti = t[i];
    float T = decode_T(Tp);
    atomicAdd(&contrib[d], 1.0f - __expf(-BETA * (T - ti)));
    int c = i >> 5;
    if (c < CCH - 1){                       // last chunk's carry is unused
      float tn = t[(c+1)*LCH];
      atomicAdd(&SL[(size_t)c * D_DIM + d], __expf(-BETA * (tn - ti)));
    }
  } else {
    int c = (b-72)*256 + tid;               // c in [0,512)
    float tc = t[c*LCH];
    dchunk[c] = (c < CCH-1) ? __expf(-BETA * (t[(c+1)*LCH] - tc)) : 1.0f;
    int s0c = (c >> 5) << 5;                // segment-start chunk
    cumdec[c] = __expf(-BETA * (tc - t[s0c*LCH]));
    if (b == 72 && tid < NSEG){
      int s = tid;
      Aseg[s] = (s < NSEG-1)
        ? __expf(-BETA * (t[(s+1)*SEG*LCH] - t[s*SEG*LCH])) : 1.0f;
    }
  }
}

// Fused (identical to R8): blocks [0,128) = per-segment local exclusive scan
// of SL (in-place, carry-out per segment); blocks [128,640) = sA =
// bf16(softplus(log_alpha)) + integral partial acc[1].
__global__ void k_scan_alpha(float* __restrict__ SL,
                             const float* __restrict__ dchunk,
                             float* __restrict__ Carry,
                             const float* __restrict__ la,
                             const float* __restrict__ contrib,
                             unsigned short* __restrict__ sA,
                             float* __restrict__ acc){
  const int b = blockIdx.x, tid = threadIdx.x;
  if (b < 128){
    const int seg = b >> 3, jb = b & 7;
    const int j = jb*256 + tid;
    const int c0 = seg * SEG;
    const size_t base = (size_t)c0 * D_DIM + j;
    float u = 0.f;
    float cur[4], nxt[4];
    #pragma unroll
    for (int q = 0; q < 4; ++q) cur[q] = SL[base + (size_t)q * D_DIM];
    for (int g = 0; g < SEG; g += 4){
      #pragma unroll
      for (int q = 0; q < 4; ++q)
        nxt[q] = (g+4 < SEG) ? SL[base + (size_t)(g+4+q) * D_DIM] : 0.f;
      #pragma unroll
      for (int q = 0; q < 4; ++q){
        int c = c0 + g + q;
        float l = cur[q];
        SL[(size_t)c * D_DIM + j] = u;
        u = fmaf(dchunk[c], u, l);
      }
      #pragma unroll
      for (int q = 0; q < 4; ++q) cur[q] = nxt[q];
    }
    Carry[(size_t)seg * D_DIM + j] = u;
    return;
  }
  const int nthreads = 512*256;               // alpha-range threads
  int atid = (b-128)*256 + tid;
  const float4* la4 = (const float4*)la;
  ushort4* sA4 = (ushort4*)sA;
  float p = 0.f;
  #pragma unroll
  for (int u = 0; u < 8; ++u){
    int i4 = atid + u * nthreads;
    float4 x = la4[i4];
    float4 sp;
    sp.x = softplus_f(x.x); sp.y = softplus_f(x.y);
    sp.z = softplus_f(x.z); sp.w = softplus_f(x.w);
    ushort4 h;
    h.x = f2bf(sp.x); h.y = f2bf(sp.y); h.z = f2bf(sp.z); h.w = f2bf(sp.w);
    sA4[i4] = h;
    int col = (i4 * 4) & (D_DIM - 1);
    p = fmaf(sp.x, contrib[col+0], p);
    p = fmaf(sp.y, contrib[col+1], p);
    p = fmaf(sp.z, contrib[col+2], p);
    p = fmaf(sp.w, contrib[col+3], p);
  }
  __shared__ float red[4];
  float w = wave_red(p);
  int lane = tid & 63, wid = tid >> 6;
  if (lane == 0) red[wid] = w;
  __syncthreads();
  if (tid == 0) atomicAdd(&acc[1], red[0]+red[1]+red[2]+red[3]);
}

// One block (512 thr = 8 waves) per chunk. Decomposed (no sequential S):
//   lam_k = mu[d_k] + e^{-(t_k-t0)} * (sA[d_k] . S0)
//                   + sum_{i<k} e^{-(t_k-t_i)} * sA[d_k][m_i]
// E[seg] is folded in on the fly: E = sum_{s<seg} Carry[s]*prod_{u>s} Aseg[u]
// (backward loop, weight w starts at 1). Saves the k_carry launch + E buffer.
__global__ __launch_bounds__(512) void k_events(
    const float* __restrict__ t, const int* __restrict__ m,
    const unsigned short* __restrict__ sA, const float* __restrict__ muw,
    const float* __restrict__ SL, const float* __restrict__ Carry,
    const float* __restrict__ Aseg,
    const float* __restrict__ cumdec, float* __restrict__ acc,
    const void* Tp, float* __restrict__ out){
  __shared__ float S0[D_DIM];
  __shared__ float tl[LCH];
  __shared__ int   ml[LCH];
  __shared__ float wred[8];
  const int tid = threadIdx.x;          // 0..511
  const int c = blockIdx.x;
  const int seg = c >> 5;
  const float cd = cumdec[c];

  {
    const float4 sv = *(const float4*)(SL + (size_t)c * D_DIM + tid*4);
    // entering-state for this segment, computed in-block (backward weights)
    float4 e = {0.f, 0.f, 0.f, 0.f};
    float wgt = 1.f;
    for (int s = seg - 1; s >= 0; --s){
      const float4 cr = *(const float4*)(Carry + (size_t)s * D_DIM + tid*4);
      e.x = fmaf(cr.x, wgt, e.x); e.y = fmaf(cr.y, wgt, e.y);
      e.z = fmaf(cr.z, wgt, e.z); e.w = fmaf(cr.w, wgt, e.w);
      wgt *= Aseg[s];
    }
    float4 s;
    s.x = fmaf(e.x, cd, sv.x); s.y = fmaf(e.y, cd, sv.y);
    s.z = fmaf(e.z, cd, sv.z); s.w = fmaf(e.w, cd, sv.w);
    *(float4*)&S0[tid*4] = s;
  }
  if (tid < LCH){
    ml[tid] = m[c*LCH + tid];
    tl[tid] = t[c*LCH + tid];
  }
  __syncthreads();

  const int l = tid & 63, w = tid >> 6;
  const int l4 = l * 4;

  // lane's 32 S0 columns -> registers (one-time)
  float4 s0[8];
  #pragma unroll
  for (int u = 0; u < 8; ++u) s0[u] = *(const float4*)&S0[u*256 + l4];

  const float t0 = tl[0];
  float lgw = 0.f;
  #pragma unroll
  for (int q = 0; q < 4; ++q){
    const int k = w*4 + q;
    const int d = ml[k];
    const unsigned short* row = sA + (size_t)d * D_DIM;
    float p = 0.f;
    #pragma unroll
    for (int u = 0; u < 8; ++u){
      ushort4 a = *(const ushort4*)(row + u*256 + l4);
      p = fmaf(bf2f(a.x), s0[u].x, p);
      p = fmaf(bf2f(a.y), s0[u].y, p);
      p = fmaf(bf2f(a.z), s0[u].z, p);
      p = fmaf(bf2f(a.w), s0[u].w, p);
    }
    const float tk = tl[k];
    float g = 0.f;
    if (l < k) g = bf2f(row[ml[l]]) * __expf(tl[l] - tk);  // exact pair term
    p = fmaf(p, __expf(t0 - tk), g);
    float v = wave_red(p);
    if (l == 0) lgw += __logf(muw[d] + v + 1e-8f);
  }
  if (l == 0) wred[w] = lgw;
  __syncthreads();
  if (tid == 0){
    float lg = ((wred[0]+wred[1])+(wred[2]+wred[3]))
             + ((wred[4]+wred[5])+(wred[6]+wred[7]));
    atomicAdd(&acc[0], lg);
    __threadfence();                        // publish before taking ticket
    unsigned old = atomicAdd((unsigned*)&acc[3], 1u);
    if (old == CCH - 1){                    // last block: finalize
      float a0 = atomicAdd(&acc[0], 0.0f);  // device-scope reads
      float a1 = atomicAdd(&acc[1], 0.0f);
      float a2 = atomicAdd(&acc[2], 0.0f);
      float T = decode_T(Tp);
      out[0] = a0 - (T * a2 + a1 * (1.0f / BETA));
    }
  }
}

extern "C" void kernel_launch(void* const* d_in, const int* in_sizes, int n_in,
                              void* d_out, int out_size, void* d_ws, size_t ws_size,
                              hipStream_t stream) {
  const float* t_events  = (const float*)d_in[0];
  const int*   marks     = (const int*)  d_in[1];
  const void*  Tp        =               d_in[2];
  const float* log_mu    = (const float*)d_in[3];
  const float* log_alpha = (const float*)d_in[4];
  float* out = (float*)d_out;

  // ws layout (floats), zeroed region first:
  // SL[CCH*D] | contrib[D] | acc[16] || Carry[NSEG*D] | muw[D]
  //   | dchunk[CCH] | cumdec[CCH] | Aseg[NSEG] | sA[D*D bf16]
  float* ws      = (float*)d_ws;
  float* SL      = ws;
  float* contrib = SL + (size_t)CCH * D_DIM;
  float* acc     = contrib + D_DIM;
  float* Carry   = acc + 16;
  float* muw     = Carry + (size_t)NSEG * D_DIM;
  float* dchunk  = muw + D_DIM;
  float* cumdec  = dchunk + CCH;
  float* Aseg    = cumdec + CCH;
  unsigned short* sA = (unsigned short*)(Aseg + NSEG);  // 16B-aligned offset

  size_t zero_floats = (size_t)CCH * D_DIM + D_DIM + 16;
  hipMemsetAsync(d_ws, 0, zero_floats * sizeof(float), stream);

  k_small     <<<74, 256, 0, stream>>>(t_events, marks, Tp, log_mu, muw,
                                       contrib, SL, dchunk, cumdec, Aseg, acc);
  k_scan_alpha<<<640, 256, 0, stream>>>(SL, dchunk, Carry, log_alpha,
                                        contrib, sA, acc);
  k_events    <<<CCH, 512, 0, stream>>>(t_events, marks, sA, muw,
                                        SL, Carry, Aseg, cumdec, acc, Tp, out);
}